// Round 10
// baseline (401.274 us; speedup 1.0000x reference)
//
#include <hip/hip_runtime.h>
#include <hip/hip_fp16.h>
#include <cmath>

#define TEMP 10.0f
#define TPB 512           // scatter block size
#define TILE 2048         // edges per scatter block (one tile per block)
#define GSZ 200           // nodes per bucket (non-pow2: balance gather grid ~2 blocks/CU)
#define BMAX 512          // max buckets supported by scatter LDS tables
#define GTPB 1024         // gather block size
#define CAP 44            // per-node slot capacity in gather (overflow handled)
#define OV 8192           // global overflow FIFO records (never used in practice)

typedef float v2f  __attribute__((ext_vector_type(2)));
typedef float vf4  __attribute__((ext_vector_type(4)));

__device__ __forceinline__ int   nt_i (const int* p)   { return __builtin_nontemporal_load(p); }
__device__ __forceinline__ float nt_f (const float* p) { return __builtin_nontemporal_load(p); }
__device__ __forceinline__ float4 nt_f4(const float4* p) {
    vf4 v = __builtin_nontemporal_load((const vf4*)p);
    return make_float4(v.x, v.y, v.z, v.w);
}

__device__ __forceinline__ void pk_fadd(float* p, float a, float b) {
#if __has_builtin(__builtin_amdgcn_global_atomic_fadd_v2f32)
    v2f v; v.x = a; v.y = b;
    __builtin_amdgcn_global_atomic_fadd_v2f32(
        (__attribute__((address_space(1))) v2f*)p, v);
#else
    atomicAdd(p, a); atomicAdd(p + 1, b);
#endif
}

__device__ __forceinline__ void hamilton(float4 a, float4 b,
                                         float& ow, float& ox, float& oy, float& oz) {
    ow = a.x*b.x - a.y*b.y - a.z*b.z - a.w*b.w;
    ox = a.x*b.y + a.y*b.x + a.z*b.w - a.w*b.z;
    oy = a.x*b.z - a.y*b.w + a.z*b.x + a.w*b.y;
    oz = a.x*b.w + a.y*b.z - a.z*b.y + a.w*b.x;
}

__device__ __forceinline__ unsigned f2h(float x) {
    return (unsigned)__half_as_ushort(__float2half_rn(x));
}
__device__ __forceinline__ float h2f(unsigned u) {
    return __half2float(__ushort_as_half((unsigned short)(u & 0xFFFFu)));
}

// ---------- scatter: tile-sort + per-tile global reservation (no hist/scan passes) ----------
// ws: cnt[B] u32 | ovfcur u32 | pad | fifo[OV] uint4 | pay[3*B*capB] u32 | dlarr[B*capB] u16
__global__ void __launch_bounds__(TPB)
scatter_res_kernel(const float* __restrict__ nl, const float4* __restrict__ nq,
                   const float4* __restrict__ erq, const float* __restrict__ ew,
                   const int* __restrict__ src, const int* __restrict__ dst,
                   unsigned* __restrict__ cnt, unsigned* __restrict__ ovfcur,
                   uint4* __restrict__ fifo,
                   unsigned* __restrict__ pay, unsigned short* __restrict__ dlarr,
                   int E, int B, int capB) {
    __shared__ unsigned sy[TILE], sz[TILE], sw[TILE], gsl[TILE];  // 32 KB
    __shared__ unsigned short sdl[TILE];                          //  4 KB
    __shared__ unsigned th[BMAX], basec[BMAX], curt[BMAX], resv[BMAX]; // 8 KB

    int tid = threadIdx.x;
    int ts = blockIdx.x * TILE;
    int tE = E - ts; if (tE > TILE) tE = TILE;

    for (int b = tid; b < B; b += TPB) th[b] = 0;
    __syncthreads();
    // tile histogram
    for (int k = tid; k < tE; k += TPB)
        atomicAdd(&th[((unsigned)dst[ts + k]) / GSZ], 1u);
    __syncthreads();
    // single-wave exclusive scan over B buckets + global reservation per bucket
    if (tid < 64) {
        unsigned vals[8]; unsigned tot = 0;
        #pragma unroll
        for (int c = 0; c < 8; ++c) {
            int i = tid * 8 + c;
            vals[c] = (i < B) ? th[i] : 0u;
            tot += vals[c];
        }
        unsigned inc = tot;
        #pragma unroll
        for (int off = 1; off < 64; off <<= 1) {
            unsigned up = __shfl_up(inc, off);
            if (tid >= off) inc += up;
        }
        unsigned run = inc - tot;     // exclusive prefix
        #pragma unroll
        for (int c = 0; c < 8; ++c) {
            int i = tid * 8 + c;
            if (i < B) {
                basec[i] = run; curt[i] = run;
                resv[i] = vals[c] ? atomicAdd(&cnt[i], vals[c]) : 0u;
            }
            run += vals[c];
        }
    }
    __syncthreads();
    // compute payloads, place bucket-sorted into LDS stage
    for (int k = tid; k < tE; k += TPB) {
        int e = ts + k;
        int s_ = nt_i(&src[e]);
        unsigned d = (unsigned)dst[e];
        float l = nl[s_];
        float p = __expf(TEMP * nt_f(&ew[e]) * l);
        float ow, ox, oy, oz;
        hamilton(nt_f4(&erq[e]), nq[s_], ow, ox, oy, oz);
        unsigned bu = d / GSZ;
        unsigned pos = atomicAdd(&curt[bu], 1u);
        unsigned y = f2h(p)      | (f2h(p * l)  << 16);
        unsigned z = f2h(p * ow) | (f2h(p * ox) << 16);
        unsigned w = f2h(p * oy) | (f2h(p * oz) << 16);
        sy[pos] = y; sz[pos] = z; sw[pos] = w;
        sdl[pos] = (unsigned short)(d - bu * GSZ);
        unsigned off = resv[bu] + (pos - basec[bu]);
        if (off < (unsigned)capB) {
            gsl[pos] = bu * (unsigned)capB + off;
        } else {
            gsl[pos] = 0xFFFFFFFFu;              // region overflow (+12 sigma: ~never)
            unsigned o = atomicAdd(ovfcur, 1u);
            if (o < OV) { uint4 f; f.x = d; f.y = y; f.z = z; f.w = w; fifo[o] = f; }
        }
    }
    __syncthreads();
    // flush in sorted order: consecutive lanes -> consecutive slots
    for (int k = tid; k < tE; k += TPB) {
        unsigned g = gsl[k];
        if (g != 0xFFFFFFFFu) {
            size_t base = 3 * (size_t)g;
            pay[base] = sy[k]; pay[base + 1] = sz[k]; pay[base + 2] = sw[k];
            dlarr[g] = sdl[k];
        }
    }
}

// ---------- gather: per-bucket counting-sort by node + register reduce ----------
__global__ void __launch_bounds__(GTPB)
gather_seg_kernel(const float* __restrict__ nl, const float4* __restrict__ nq,
                  const unsigned* __restrict__ cnt, const unsigned* __restrict__ ovfcur,
                  const uint4* __restrict__ fifo,
                  const unsigned* __restrict__ pay, const unsigned short* __restrict__ dlarr,
                  int capB,
                  float4* __restrict__ out_q, float* __restrict__ out_l, int N) {
    __shared__ unsigned short idx[GSZ * CAP];   // 17.6 KB
    __shared__ int   curn[GSZ];
    __shared__ float ovfa[GSZ * 7];
    int b = blockIdx.x, tid = threadIdx.x;
    for (int i = tid; i < GSZ; i += GTPB) curn[i] = 0;
    for (int i = tid; i < GSZ * 7; i += GTPB) ovfa[i] = 0.f;
    __syncthreads();

    int M = (int)cnt[b]; if (M > capB) M = capB;
    const unsigned* pb = pay + 3 * (size_t)b * capB;
    const unsigned short* db = dlarr + (size_t)b * capB;

    // phase 1: one LDS atomic per record -> per-node index lists (2B/record read)
    for (int i = tid; i < M; i += GTPB) {
        int dl = db[i];
        int slot = atomicAdd(&curn[dl], 1);
        if (slot < CAP) {
            idx[dl * CAP + slot] = (unsigned short)i;
        } else {
            unsigned y = pb[3*(size_t)i], z = pb[3*(size_t)i+1], w = pb[3*(size_t)i+2];
            float* a = &ovfa[dl * 7];
            atomicAdd(a + 0, h2f(y)); atomicAdd(a + 1, h2f(y >> 16));
            atomicAdd(a + 2, h2f(z)); atomicAdd(a + 3, h2f(z >> 16));
            atomicAdd(a + 4, h2f(w)); atomicAdd(a + 5, h2f(w >> 16));
        }
    }
    // drain global overflow FIFO (count is 0 in practice)
    unsigned on = *ovfcur; if (on > OV) on = OV;
    for (unsigned i = tid; i < on; i += GTPB) {
        uint4 f = fifo[i];
        unsigned loc = f.x - (unsigned)b * GSZ;
        if (loc < GSZ) {
            float* a = &ovfa[loc * 7];
            atomicAdd(a + 0, h2f(f.y)); atomicAdd(a + 1, h2f(f.y >> 16));
            atomicAdd(a + 2, h2f(f.z)); atomicAdd(a + 3, h2f(f.z >> 16));
            atomicAdd(a + 4, h2f(f.w)); atomicAdd(a + 5, h2f(f.w >> 16));
        }
    }
    __syncthreads();

    // phase 2: 4 threads per node, register accumulation (segment is L1/L2-hot)
    int j = tid >> 2, r = tid & 3;
    if (j < GSZ) {
        int deg = curn[j]; if (deg > CAP) deg = CAP;
        float aZ = 0.f, aL = 0.f, a0 = 0.f, a1 = 0.f, a2 = 0.f, a3 = 0.f;
        for (int s = r; s < deg; s += 4) {
            int i = idx[j * CAP + s];
            unsigned y = pb[3*(size_t)i], z = pb[3*(size_t)i+1], w = pb[3*(size_t)i+2];
            aZ += h2f(y); aL += h2f(y >> 16);
            a0 += h2f(z); a1 += h2f(z >> 16);
            a2 += h2f(w); a3 += h2f(w >> 16);
        }
        for (int m = 1; m <= 2; m <<= 1) {
            aZ += __shfl_xor(aZ, m); aL += __shfl_xor(aL, m);
            a0 += __shfl_xor(a0, m); a1 += __shfl_xor(a1, m);
            a2 += __shfl_xor(a2, m); a3 += __shfl_xor(a3, m);
        }
        if (r == 0) {
            int n = b * GSZ + j;
            if (n < N) {
                const float* o = &ovfa[j * 7];
                float l = nl[n];
                float ps = __expf(TEMP * l);
                float Z  = aZ + o[0] + ps;
                float sl = aL + o[1] + ps * l;
                float4 q = nq[n];
                float qw = a0 + o[2] + ps * q.x;
                float qx = a1 + o[3] + ps * q.y;
                float qy = a2 + o[4] + ps * q.z;
                float qz = a3 + o[5] + ps * q.w;
                float inv = 1.0f / Z;
                qw *= inv; qx *= inv; qy *= inv; qz *= inv;
                float norm = fmaxf(sqrtf(qw*qw + qx*qx + qy*qy + qz*qz), 1e-12f);
                float rn = 1.0f / norm;
                out_q[n] = make_float4(qw * rn, qx * rn, qy * rn, qz * rn);
                out_l[n] = sl * inv;
            }
        }
    }
}

// ---------------- fallback path (R3) ----------------
__global__ void __launch_bounds__(256)
scatter_kernel(const int* __restrict__ dst, int* __restrict__ cnt,
               int* __restrict__ bucket, int cap,
               const float* __restrict__ node_levels, const float4* __restrict__ node_q,
               const float4* __restrict__ edge_rel_q, const float* __restrict__ edge_w,
               const int* __restrict__ src, float* __restrict__ side, int E) {
    int e = blockIdx.x * blockDim.x + threadIdx.x;
    if (e >= E) return;
    int d = dst[e];
    int slot = atomicAdd(&cnt[d], 1);
    if (slot < cap) {
        bucket[(long long)d * cap + slot] = e;
    } else {
        int s = src[e];
        float l = node_levels[s];
        float p = __expf(TEMP * edge_w[e] * l);
        float ow, ox, oy, oz;
        hamilton(edge_rel_q[e], node_q[s], ow, ox, oy, oz);
        float* rec = side + 6 * (long long)d;
        pk_fadd(rec + 0, p,      p * l);
        pk_fadd(rec + 2, p * ow, p * ox);
        pk_fadd(rec + 4, p * oy, p * oz);
    }
}

__global__ void __launch_bounds__(256)
gather_kernel(const float* __restrict__ node_levels, const float4* __restrict__ node_q,
              const float4* __restrict__ edge_rel_q, const float* __restrict__ edge_w,
              const int* __restrict__ src, const int* __restrict__ cnt,
              const int* __restrict__ bucket, int cap, const float* __restrict__ side,
              float4* __restrict__ out_q, float* __restrict__ out_l, int N) {
    int tid  = blockIdx.x * blockDim.x + threadIdx.x;
    int wave = tid >> 6, lane = tid & 63, half = lane >> 5, sub = lane & 31;
    int n = wave * 2 + half;
    float aZ = 0.f, aL = 0.f, a0 = 0.f, a1 = 0.f, a2 = 0.f, a3 = 0.f;
    if (n < N) {
        int deg = cnt[n]; if (deg > cap) deg = cap;
        const int* bkt = bucket + (long long)n * cap;
        for (int s = sub; s < deg; s += 32) {
            int e = bkt[s];
            int sn = src[e];
            float l = node_levels[sn];
            float p = __expf(TEMP * edge_w[e] * l);
            float ow, ox, oy, oz;
            hamilton(edge_rel_q[e], node_q[sn], ow, ox, oy, oz);
            aZ += p; aL += p * l; a0 += p * ow; a1 += p * ox; a2 += p * oy; a3 += p * oz;
        }
    }
    for (int m = 16; m; m >>= 1) {
        aZ += __shfl_xor(aZ, m); aL += __shfl_xor(aL, m);
        a0 += __shfl_xor(a0, m); a1 += __shfl_xor(a1, m);
        a2 += __shfl_xor(a2, m); a3 += __shfl_xor(a3, m);
    }
    if (sub == 0 && n < N) {
        const float* rec = side + 6 * (long long)n;
        float l  = node_levels[n];
        float ps = __expf(TEMP * l);
        float Z  = aZ + rec[0] + ps;
        float sl = aL + rec[1] + ps * l;
        float4 q = node_q[n];
        float qw = a0 + rec[2] + ps * q.x;
        float qx = a1 + rec[3] + ps * q.y;
        float qy = a2 + rec[4] + ps * q.z;
        float qz = a3 + rec[5] + ps * q.w;
        float inv = 1.0f / Z;
        qw *= inv; qx *= inv; qy *= inv; qz *= inv;
        float norm = fmaxf(sqrtf(qw*qw + qx*qx + qy*qy + qz*qz), 1e-12f);
        float rn = 1.0f / norm;
        out_q[n] = make_float4(qw * rn, qx * rn, qy * rn, qz * rn);
        out_l[n] = sl * inv;
    }
}

extern "C" void kernel_launch(void* const* d_in, const int* in_sizes, int n_in,
                              void* d_out, int out_size, void* d_ws, size_t ws_size,
                              hipStream_t stream) {
    const float*  node_levels = (const float*)d_in[0];
    const float4* node_q      = (const float4*)d_in[1];
    const float4* edge_rel_q  = (const float4*)d_in[2];
    const float*  edge_w      = (const float*)d_in[3];
    const int*    src         = (const int*)d_in[4];
    const int*    dst         = (const int*)d_in[5];

    const int N = in_sizes[0];
    const int E = in_sizes[3];

    const int B = (N + GSZ - 1) / GSZ;   // 500 buckets at N=100K

    // ws layout: cnt[B] | ovfcur | pad16 | fifo[OV] uint4 | pay[3*B*capB] u32 | dlarr[B*capB] u16
    size_t fifo_off = (((size_t)(B + 1) * 4) + 15) & ~(size_t)15;
    size_t pay_off  = fifo_off + (size_t)OV * 16;

    long long availCap = ((long long)ws_size - (long long)pay_off) / (14LL * B);
    int meanB  = E / B;
    int minCap = meanB + 6 * (int)std::sqrt((double)meanB) + 8;
    int capB   = (availCap > 16000) ? 16000 : (int)availCap;

    if (capB >= minCap && B <= BMAX && meanB < 32000) {
        unsigned*       cnt    = (unsigned*)d_ws;
        unsigned*       ovfc   = cnt + B;
        uint4*          fifo   = (uint4*)((char*)d_ws + fifo_off);
        unsigned*       pay    = (unsigned*)((char*)d_ws + pay_off);
        unsigned short* dlarr  = (unsigned short*)((char*)d_ws + pay_off + 12ull * B * capB);

        hipMemsetAsync(d_ws, 0, (size_t)(B + 1) * 4, stream);

        int nblk = (E + TILE - 1) / TILE;
        scatter_res_kernel<<<nblk, TPB, 0, stream>>>(
            node_levels, node_q, edge_rel_q, edge_w, src, dst,
            cnt, ovfc, fifo, pay, dlarr, E, B, capB);
        gather_seg_kernel<<<B, GTPB, 0, stream>>>(
            node_levels, node_q, cnt, ovfc, fifo, pay, dlarr, capB,
            (float4*)d_out, (float*)d_out + 4 * (long long)N, N);
    } else {
        // R3 fallback
        const int tpb = 256;
        size_t cnt_elems  = ((size_t)N + 3) & ~(size_t)3;
        size_t side_elems = 6 * (size_t)N;
        size_t head_bytes = (cnt_elems + side_elems) * 4;
        int cap = 0;
        for (int c : {128, 64}) {
            if (head_bytes + (size_t)N * c * 4 <= ws_size) { cap = c; break; }
        }
        int*   fcnt   = (int*)d_ws;
        float* side   = (float*)d_ws + cnt_elems;
        int*   bucket = (int*)d_ws + cnt_elems + side_elems;
        hipMemsetAsync(d_ws, 0, head_bytes, stream);
        scatter_kernel<<<(E + tpb - 1) / tpb, tpb, 0, stream>>>(
            dst, fcnt, bucket, cap, node_levels, node_q, edge_rel_q, edge_w, src, side, E);
        int waves  = (N + 1) / 2;
        int blocks = (waves * 64 + tpb - 1) / tpb;
        gather_kernel<<<blocks, tpb, 0, stream>>>(
            node_levels, node_q, edge_rel_q, edge_w, src, fcnt, bucket, cap, side,
            (float4*)d_out, (float*)d_out + 4 * (long long)N, N);
    }
}

// Round 11
// 328.706 us; speedup vs baseline: 1.2208x; 1.2208x over previous
//
#include <hip/hip_runtime.h>
#include <hip/hip_fp16.h>
#include <cmath>

#define TEMP 10.0f
#define TPB 512           // scatter block size
#define NBLK 768          // scatter grid (3 blocks/CU)
#define SHIFT 9
#define GSZ 512           // nodes per bucket = 1<<SHIFT
#define BMAX 256          // max buckets supported by scatter LDS tables
#define TILE 2048         // edges per scatter tile
#define GTPB 1024         // gather block size
#define CAP 44            // per-node slot capacity in gather (overflow handled)
#define OV 8192           // global overflow FIFO records (expected use: ~500)

typedef float v2f  __attribute__((ext_vector_type(2)));
typedef float vf4  __attribute__((ext_vector_type(4)));
typedef unsigned uv4 __attribute__((ext_vector_type(4)));

__device__ __forceinline__ int   nt_i (const int* p)   { return __builtin_nontemporal_load(p); }
__device__ __forceinline__ float nt_f (const float* p) { return __builtin_nontemporal_load(p); }
__device__ __forceinline__ float4 nt_f4(const float4* p) {
    vf4 v = __builtin_nontemporal_load((const vf4*)p);
    return make_float4(v.x, v.y, v.z, v.w);
}
__device__ __forceinline__ uint4 nt_u4(const uint4* p) {
    uv4 v = __builtin_nontemporal_load((const uv4*)p);
    uint4 r; r.x = v.x; r.y = v.y; r.z = v.z; r.w = v.w; return r;
}

__device__ __forceinline__ void pk_fadd(float* p, float a, float b) {
#if __has_builtin(__builtin_amdgcn_global_atomic_fadd_v2f32)
    v2f v; v.x = a; v.y = b;
    __builtin_amdgcn_global_atomic_fadd_v2f32(
        (__attribute__((address_space(1))) v2f*)p, v);
#else
    atomicAdd(p, a); atomicAdd(p + 1, b);
#endif
}

__device__ __forceinline__ void hamilton(float4 a, float4 b,
                                         float& ow, float& ox, float& oy, float& oz) {
    ow = a.x*b.x - a.y*b.y - a.z*b.z - a.w*b.w;
    ox = a.x*b.y + a.y*b.x + a.z*b.w - a.w*b.z;
    oy = a.x*b.z - a.y*b.w + a.z*b.x + a.w*b.y;
    oz = a.x*b.w + a.y*b.z - a.z*b.y + a.w*b.x;
}

__device__ __forceinline__ unsigned f2h(float x) {
    return (unsigned)__half_as_ushort(__float2half_rn(x));
}
__device__ __forceinline__ float h2f(unsigned u) {
    return __half2float(__ushort_as_half((unsigned short)(u & 0xFFFFu)));
}

// ---------- scatter: tile-sort + per-tile global reservation (no hist/scan passes) ----------
// ws: cnt[B] u32 | ovfcur u32 | pad16 | fifo[OV] uint4 | buckets[B*capB] uint4
// bucket record: x = dl | f2h(p)<<16 ; y = f2h(p*l) | f2h(p*q0)<<16 ; z,w = rest
// FIFO record:   x = d (17b) | f2h(p)<<17 is impossible -> x = d, y = f2h(p) | f2h(p*l)<<16,
//                z = f2h(p*q0) | f2h(p*q1)<<16, w = f2h(p*q2) | f2h(p*q3)<<16
__global__ void __launch_bounds__(TPB)
scatter_res_kernel(const float* __restrict__ nl, const float4* __restrict__ nq,
                   const float4* __restrict__ erq, const float* __restrict__ ew,
                   const int* __restrict__ src, const int* __restrict__ dst,
                   unsigned* __restrict__ cnt, unsigned* __restrict__ ovfcur,
                   uint4* __restrict__ fifo, uint4* __restrict__ buckets,
                   int E, int B, int capB, int span) {
    __shared__ uint4    stage[TILE];     // 32 KB
    __shared__ unsigned gslot[TILE];     //  8 KB
    __shared__ unsigned th[BMAX], basec[BMAX], curt[BMAX], resv[BMAX];

    int blk = blockIdx.x, tid = threadIdx.x;
    int start = blk * span;
    int end = start + span; if (end > E) end = E;

    for (int ts = start; ts < end; ts += TILE) {
        int tE = end - ts; if (tE > TILE) tE = TILE;
        for (int b = tid; b < B; b += TPB) th[b] = 0;
        __syncthreads();
        for (int k = tid; k < tE; k += TPB)
            atomicAdd(&th[((unsigned)dst[ts + k]) >> SHIFT], 1u);
        __syncthreads();
        if (tid < 64) {
            unsigned vals[4]; unsigned tot = 0;
            #pragma unroll
            for (int c = 0; c < 4; ++c) {
                int i = tid * 4 + c;
                vals[c] = (i < B) ? th[i] : 0u;
                tot += vals[c];
            }
            unsigned inc = tot;
            #pragma unroll
            for (int off = 1; off < 64; off <<= 1) {
                unsigned up = __shfl_up(inc, off);
                if (tid >= off) inc += up;
            }
            unsigned run = inc - tot;
            #pragma unroll
            for (int c = 0; c < 4; ++c) {
                int i = tid * 4 + c;
                if (i < B) {
                    basec[i] = run; curt[i] = run;
                    resv[i] = vals[c] ? atomicAdd(&cnt[i], vals[c]) : 0u;
                }
                run += vals[c];
            }
        }
        __syncthreads();
        for (int k = tid; k < tE; k += TPB) {
            int e = ts + k;
            int s_ = nt_i(&src[e]);
            unsigned d = (unsigned)dst[e];
            float l = nl[s_];
            float p = __expf(TEMP * nt_f(&ew[e]) * l);
            float ow, ox, oy, oz;
            hamilton(nt_f4(&erq[e]), nq[s_], ow, ox, oy, oz);
            unsigned bu = d >> SHIFT;
            unsigned pos = atomicAdd(&curt[bu], 1u);
            uint4 pk;
            pk.x = (d & (GSZ - 1)) | (f2h(p) << 16);
            pk.y = f2h(p * l)  | (f2h(p * ow) << 16);
            pk.z = f2h(p * ox) | (f2h(p * oy) << 16);
            pk.w = f2h(p * oz);
            stage[pos] = pk;
            unsigned off = resv[bu] + (pos - basec[bu]);
            if (off < (unsigned)capB) {
                gslot[pos] = bu * (unsigned)capB + off;
            } else {
                gslot[pos] = 0xFFFFFFFFu;
                unsigned o = atomicAdd(ovfcur, 1u);
                if (o < OV) {
                    uint4 f;
                    f.x = d;
                    f.y = f2h(p)      | (f2h(p * l)  << 16);
                    f.z = f2h(p * ow) | (f2h(p * ox) << 16);
                    f.w = f2h(p * oy) | (f2h(p * oz) << 16);
                    fifo[o] = f;
                }
            }
        }
        __syncthreads();
        for (int k = tid; k < tE; k += TPB) {
            unsigned g = gslot[k];
            if (g != 0xFFFFFFFFu) buckets[g] = stage[k];
        }
        __syncthreads();
    }
}

// ---------- gather: per-bucket counting-sort by node + register reduce ----------
__global__ void __launch_bounds__(GTPB)
gather_pay_kernel(const float* __restrict__ nl, const float4* __restrict__ nq,
                  const unsigned* __restrict__ cnt, const unsigned* __restrict__ ovfcur,
                  const uint4* __restrict__ fifo, const uint4* __restrict__ buckets,
                  int capB,
                  float4* __restrict__ out_q, float* __restrict__ out_l, int N) {
    __shared__ unsigned short idx[GSZ * CAP];   // 45 KB
    __shared__ int   curn[GSZ];                 //  2 KB
    __shared__ float ovfa[GSZ * 7];             // 14 KB
    int b = blockIdx.x, tid = threadIdx.x;
    for (int i = tid; i < GSZ; i += GTPB) curn[i] = 0;
    for (int i = tid; i < GSZ * 7; i += GTPB) ovfa[i] = 0.f;
    __syncthreads();

    int M = (int)cnt[b]; if (M > capB) M = capB;
    const uint4* seg = buckets + (size_t)b * capB;
    const unsigned* bx = (const unsigned*)seg;

    // phase 1: one LDS atomic per record -> per-node index lists
    for (int i = tid; i < M; i += GTPB) {
        unsigned w0 = bx[4 * (size_t)i];
        unsigned dl = w0 & (GSZ - 1);
        int slot = atomicAdd(&curn[dl], 1);
        if (slot < CAP) {
            idx[dl * CAP + slot] = (unsigned short)i;
        } else {
            uint4 pk = seg[i];
            float* a = &ovfa[dl * 7];
            atomicAdd(a + 0, h2f(pk.x >> 16));
            atomicAdd(a + 1, h2f(pk.y));
            atomicAdd(a + 2, h2f(pk.y >> 16));
            atomicAdd(a + 3, h2f(pk.z));
            atomicAdd(a + 4, h2f(pk.z >> 16));
            atomicAdd(a + 5, h2f(pk.w));
        }
    }
    // drain global overflow FIFO (expected ~hundreds of records, total)
    unsigned on = *ovfcur; if (on > OV) on = OV;
    for (unsigned i = tid; i < on; i += GTPB) {
        uint4 f = fifo[i];
        unsigned loc = f.x - (unsigned)b * GSZ;
        if (loc < GSZ) {
            float* a = &ovfa[loc * 7];
            atomicAdd(a + 0, h2f(f.y));        // p
            atomicAdd(a + 1, h2f(f.y >> 16));  // p*l
            atomicAdd(a + 2, h2f(f.z));        // p*q0
            atomicAdd(a + 3, h2f(f.z >> 16));  // p*q1
            atomicAdd(a + 4, h2f(f.w));        // p*q2
            atomicAdd(a + 5, h2f(f.w >> 16));  // p*q3
        }
    }
    __syncthreads();

    // phase 2: 4 threads per node, 2 rounds
    for (int half = 0; half < (GSZ * 4) / GTPB; ++half) {
        int j = half * (GTPB / 4) + (tid >> 2);
        int r = tid & 3;
        int deg = curn[j]; if (deg > CAP) deg = CAP;
        float aZ = 0.f, aL = 0.f, a0 = 0.f, a1 = 0.f, a2 = 0.f, a3 = 0.f;
        for (int s = r; s < deg; s += 4) {
            int i = idx[j * CAP + s];
            uint4 pk = nt_u4(&seg[i]);
            aZ += h2f(pk.x >> 16);
            aL += h2f(pk.y);
            a0 += h2f(pk.y >> 16);
            a1 += h2f(pk.z);
            a2 += h2f(pk.z >> 16);
            a3 += h2f(pk.w);
        }
        for (int m = 1; m <= 2; m <<= 1) {
            aZ += __shfl_xor(aZ, m); aL += __shfl_xor(aL, m);
            a0 += __shfl_xor(a0, m); a1 += __shfl_xor(a1, m);
            a2 += __shfl_xor(a2, m); a3 += __shfl_xor(a3, m);
        }
        if (r == 0) {
            int n = b * GSZ + j;
            if (n < N) {
                const float* o = &ovfa[j * 7];
                float l = nl[n];
                float ps = __expf(TEMP * l);
                float Z  = aZ + o[0] + ps;
                float sl = aL + o[1] + ps * l;
                float4 q = nq[n];
                float qw = a0 + o[2] + ps * q.x;
                float qx = a1 + o[3] + ps * q.y;
                float qy = a2 + o[4] + ps * q.z;
                float qz = a3 + o[5] + ps * q.w;
                float inv = 1.0f / Z;
                qw *= inv; qx *= inv; qy *= inv; qz *= inv;
                float norm = fmaxf(sqrtf(qw*qw + qx*qx + qy*qy + qz*qz), 1e-12f);
                float rn = 1.0f / norm;
                out_q[n] = make_float4(qw * rn, qx * rn, qy * rn, qz * rn);
                out_l[n] = sl * inv;
            }
        }
    }
}

// ---------------- fallback path (R3) ----------------
__global__ void __launch_bounds__(256)
scatter_kernel(const int* __restrict__ dst, int* __restrict__ cnt,
               int* __restrict__ bucket, int cap,
               const float* __restrict__ node_levels, const float4* __restrict__ node_q,
               const float4* __restrict__ edge_rel_q, const float* __restrict__ edge_w,
               const int* __restrict__ src, float* __restrict__ side, int E) {
    int e = blockIdx.x * blockDim.x + threadIdx.x;
    if (e >= E) return;
    int d = dst[e];
    int slot = atomicAdd(&cnt[d], 1);
    if (slot < cap) {
        bucket[(long long)d * cap + slot] = e;
    } else {
        int s = src[e];
        float l = node_levels[s];
        float p = __expf(TEMP * edge_w[e] * l);
        float ow, ox, oy, oz;
        hamilton(edge_rel_q[e], node_q[s], ow, ox, oy, oz);
        float* rec = side + 6 * (long long)d;
        pk_fadd(rec + 0, p,      p * l);
        pk_fadd(rec + 2, p * ow, p * ox);
        pk_fadd(rec + 4, p * oy, p * oz);
    }
}

__global__ void __launch_bounds__(256)
gather_kernel(const float* __restrict__ node_levels, const float4* __restrict__ node_q,
              const float4* __restrict__ edge_rel_q, const float* __restrict__ edge_w,
              const int* __restrict__ src, const int* __restrict__ cnt,
              const int* __restrict__ bucket, int cap, const float* __restrict__ side,
              float4* __restrict__ out_q, float* __restrict__ out_l, int N) {
    int tid  = blockIdx.x * blockDim.x + threadIdx.x;
    int wave = tid >> 6, lane = tid & 63, half = lane >> 5, sub = lane & 31;
    int n = wave * 2 + half;
    float aZ = 0.f, aL = 0.f, a0 = 0.f, a1 = 0.f, a2 = 0.f, a3 = 0.f;
    if (n < N) {
        int deg = cnt[n]; if (deg > cap) deg = cap;
        const int* bkt = bucket + (long long)n * cap;
        for (int s = sub; s < deg; s += 32) {
            int e = bkt[s];
            int sn = src[e];
            float l = node_levels[sn];
            float p = __expf(TEMP * edge_w[e] * l);
            float ow, ox, oy, oz;
            hamilton(edge_rel_q[e], node_q[sn], ow, ox, oy, oz);
            aZ += p; aL += p * l; a0 += p * ow; a1 += p * ox; a2 += p * oy; a3 += p * oz;
        }
    }
    for (int m = 16; m; m >>= 1) {
        aZ += __shfl_xor(aZ, m); aL += __shfl_xor(aL, m);
        a0 += __shfl_xor(a0, m); a1 += __shfl_xor(a1, m);
        a2 += __shfl_xor(a2, m); a3 += __shfl_xor(a3, m);
    }
    if (sub == 0 && n < N) {
        const float* rec = side + 6 * (long long)n;
        float l  = node_levels[n];
        float ps = __expf(TEMP * l);
        float Z  = aZ + rec[0] + ps;
        float sl = aL + rec[1] + ps * l;
        float4 q = node_q[n];
        float qw = a0 + rec[2] + ps * q.x;
        float qx = a1 + rec[3] + ps * q.y;
        float qy = a2 + rec[4] + ps * q.z;
        float qz = a3 + rec[5] + ps * q.w;
        float inv = 1.0f / Z;
        qw *= inv; qx *= inv; qy *= inv; qz *= inv;
        float norm = fmaxf(sqrtf(qw*qw + qx*qx + qy*qy + qz*qz), 1e-12f);
        float rn = 1.0f / norm;
        out_q[n] = make_float4(qw * rn, qx * rn, qy * rn, qz * rn);
        out_l[n] = sl * inv;
    }
}

extern "C" void kernel_launch(void* const* d_in, const int* in_sizes, int n_in,
                              void* d_out, int out_size, void* d_ws, size_t ws_size,
                              hipStream_t stream) {
    const float*  node_levels = (const float*)d_in[0];
    const float4* node_q      = (const float4*)d_in[1];
    const float4* edge_rel_q  = (const float4*)d_in[2];
    const float*  edge_w      = (const float*)d_in[3];
    const int*    src         = (const int*)d_in[4];
    const int*    dst         = (const int*)d_in[5];

    const int N = in_sizes[0];
    const int E = in_sizes[3];

    const int B = (N + GSZ - 1) / GSZ;   // 196 buckets at N=100K

    size_t fifo_off = (((size_t)(B + 1) * 4) + 15) & ~(size_t)15;
    size_t buck_off = fifo_off + (size_t)OV * 16;

    long long availCap = ((long long)ws_size - (long long)buck_off) / (16LL * B);
    int meanB  = E / B;
    int minCap = meanB + (int)(1.5 * std::sqrt((double)meanB)) + 8;
    int capB   = (availCap > 65535) ? 65535 : (int)availCap;

    if (capB >= minCap && B <= BMAX) {
        unsigned* cnt  = (unsigned*)d_ws;
        unsigned* ovfc = cnt + B;
        uint4*    fifo = (uint4*)((char*)d_ws + fifo_off);
        uint4*    bck  = (uint4*)((char*)d_ws + buck_off);

        hipMemsetAsync(d_ws, 0, (size_t)(B + 1) * 4, stream);

        const int span = (E + NBLK - 1) / NBLK;
        scatter_res_kernel<<<NBLK, TPB, 0, stream>>>(
            node_levels, node_q, edge_rel_q, edge_w, src, dst,
            cnt, ovfc, fifo, bck, E, B, capB, span);
        gather_pay_kernel<<<B, GTPB, 0, stream>>>(
            node_levels, node_q, cnt, ovfc, fifo, bck, capB,
            (float4*)d_out, (float*)d_out + 4 * (long long)N, N);
    } else {
        const int tpb = 256;
        size_t cnt_elems  = ((size_t)N + 3) & ~(size_t)3;
        size_t side_elems = 6 * (size_t)N;
        size_t head_bytes = (cnt_elems + side_elems) * 4;
        int cap = 0;
        for (int c : {128, 64}) {
            if (head_bytes + (size_t)N * c * 4 <= ws_size) { cap = c; break; }
        }
        int*   fcnt   = (int*)d_ws;
        float* side   = (float*)d_ws + cnt_elems;
        int*   bucket = (int*)d_ws + cnt_elems + side_elems;
        hipMemsetAsync(d_ws, 0, head_bytes, stream);
        scatter_kernel<<<(E + tpb - 1) / tpb, tpb, 0, stream>>>(
            dst, fcnt, bucket, cap, node_levels, node_q, edge_rel_q, edge_w, src, side, E);
        int waves  = (N + 1) / 2;
        int blocks = (waves * 64 + tpb - 1) / tpb;
        gather_kernel<<<blocks, tpb, 0, stream>>>(
            node_levels, node_q, edge_rel_q, edge_w, src, fcnt, bucket, cap, side,
            (float4*)d_out, (float*)d_out + 4 * (long long)N, N);
    }
}